// Round 15
// baseline (386.114 us; speedup 1.0000x reference)
//
#include <hip/hip_runtime.h>
#include <hip/hip_bf16.h>
#include <stdint.h>

typedef unsigned short u16t;
typedef float f32x4 __attribute__((ext_vector_type(4)));
typedef short bf16x8 __attribute__((ext_vector_type(8)));

#define SDIM 224

__device__ __forceinline__ float lo16(uint32_t w) { union { uint32_t u; float f; } v; v.u = w << 16; return v.f; }
__device__ __forceinline__ u16t bf1(float a) {
    union { __hip_bfloat16 h; u16t u; } c; c.h = __float2bfloat16(a); return c.u;
}
__device__ __forceinline__ uint32_t pk2(float a, float b) {
    union { __hip_bfloat162 h; uint32_t u; } c;
    c.h = __float22bfloat162_rn(make_float2(a, b));
    return c.u;
}

// ---------------------------------------------------------------------------
// Prep (unchanged from R14)
// ---------------------------------------------------------------------------
__global__ void prep_wt_kernel(const float* __restrict__ h2wA, const float* __restrict__ h2wB,
                               const float* __restrict__ h2bA, const float* __restrict__ h2bB,
                               const float* __restrict__ actw,
                               const float* __restrict__ hb1w, const float* __restrict__ hw2w,
                               const float* __restrict__ hw1w,
                               u16t* __restrict__ wtA, u16t* __restrict__ wtB,
                               u16t* __restrict__ wt2, u16t* __restrict__ wtM)
{
    const int t0 = blockIdx.x * 256 + threadIdx.x, stride = gridDim.x * 256;
    for (int e = t0; e < 34816; e += stride) {
        int j = e & 7, n = (e >> 3) & 63, kb = e >> 9;
        int k = kb * 8 + j;
        float v = 0.f;
        if (k < 512)      { int h = k & 63, i = k >> 6; v = h2wA[h * 512 + i * 64 + n]; }
        else if (k < 520) v = h2bA[(k - 512) * 64 + n];
        wtA[e] = bf1(v);
    }
    for (int e = t0; e < 26624; e += stride) {
        int j = e & 7, n = (e >> 3) & 63, kb = e >> 9;
        int k = kb * 8 + j;
        float v = 0.f;
        if (k < 384)      { int h = k & 63, i = k >> 6; v = h2wB[h * 384 + i * 64 + n]; }
        else if (k < 390) v = h2bB[(k - 384) * 64 + n];
        else if (k < 404) v = actw[(k - 390) * 64 + n];
        wtB[e] = bf1(v);
    }
    for (int e = t0; e < 4096; e += stride) {
        int j = e & 7, n = (e >> 3) & 63, kb = e >> 9;
        int k = kb * 8 + j;
        float v = (n < 32) ? hb1w[k * 32 + n] : hw2w[k * 32 + (n - 32)];
        wt2[e] = bf1(v);
    }
    for (int e = t0; e < 2048; e += stride) {
        int j = e & 7, n = (e >> 3) & 31, kb = e >> 8;
        wtM[e] = bf1(hw1w[(kb * 8 + j) * 32 + n]);
    }
}

// ---------------------------------------------------------------------------
// stage1 (unchanged from R14)
// ---------------------------------------------------------------------------
template<int DIN, int KP, int FOFF>
__device__ __forceinline__ void stage1(const float (*sx)[112], u16t* __restrict__ ps,
                                       const float* __restrict__ s_h1w, float b1r,
                                       int wave, int lane)
{
    float w1r[DIN];
#pragma unroll
    for (int i = 0; i < DIN; ++i) w1r[i] = s_h1w[i * 64 + lane];
#pragma unroll 1
    for (int ss = 0; ss < 4; ++ss) {
        const int s = wave * 4 + ss;
        const float* xr = &sx[s][FOFF];
        float psv[DIN];
#pragma unroll
        for (int i = 0; i < DIN; ++i) psv[i] = 0.f;
#pragma unroll
        for (int a = 0; a < 8; ++a) {
            float x[DIN];
            if constexpr (DIN == 8) {
                float4 v0 = *(const float4*)(xr + a * 8);
                float4 v1 = *(const float4*)(xr + a * 8 + 4);
                x[0] = v0.x; x[1] = v0.y; x[2] = v0.z; x[3] = v0.w;
                x[4] = v1.x; x[5] = v1.y; x[6] = v1.z; x[7] = v1.w;
            } else {
                float2 v0 = *(const float2*)(xr + a * 6);
                float2 v1 = *(const float2*)(xr + a * 6 + 2);
                float2 v2 = *(const float2*)(xr + a * 6 + 4);
                x[0] = v0.x; x[1] = v0.y; x[2] = v1.x; x[3] = v1.y; x[4] = v2.x; x[5] = v2.y;
            }
            float hacc = b1r;
#pragma unroll
            for (int i = 0; i < DIN; ++i) hacc += x[i] * w1r[i];
            hacc = fmaxf(hacc, 0.f);
#pragma unroll
            for (int i = 0; i < DIN; ++i) psv[i] += hacc * x[i];
        }
#pragma unroll
        for (int i = 0; i < DIN; i += 2) {
            union { __hip_bfloat162 h; struct { u16t lo, hi; } w; } c;
            c.h = __float22bfloat162_rn(make_float2(psv[i], psv[i + 1]));
            ps[s * KP + i * 64 + lane]       = c.w.lo;
            ps[s * KP + (i + 1) * 64 + lane] = c.w.hi;
        }
    }
}

// ---------------------------------------------------------------------------
// R14 kernel, phase-gated: PH=1 staging; 2 +stage1A; 3 +GEMMA;
// 4 +stage1B/GEMMB/se; 5 +hsStore/b1w2/b2; 6 full (writes out).
// PH<6 variants replicate work across grid (sbase = bid&1023) and write a
// per-thread checksum to scratch (blocks <1024 only) to keep phases live.
// ---------------------------------------------------------------------------
template<int PH>
__global__ __launch_bounds__(256, 4)
void fused_ab(const float* __restrict__ qvals, const float* __restrict__ states,
              const float* __restrict__ hs,
              const float* __restrict__ al_h1w, const float* __restrict__ al_h1b,
              const float* __restrict__ en_h1w, const float* __restrict__ en_h1b,
              const float* __restrict__ al_bias, const float* __restrict__ en_bias,
              const float* __restrict__ act_b,
              const float* __restrict__ hb1_b, const float* __restrict__ hw2_b,
              const float* __restrict__ hw1_b, const float* __restrict__ hb2_w,
              const float* __restrict__ hb2_b,
              const u16t* __restrict__ wtA, const u16t* __restrict__ wtB,
              const u16t* __restrict__ wt2, const u16t* __restrict__ wtM,
              float* __restrict__ out, float* __restrict__ scratch)
{
    constexpr int KPA = 552, KPB = 424;
    __shared__ __align__(16) char  s_un[18432];
    __shared__ __align__(16) float s_x[16][112];
    __shared__ float s_act[16][14];
    __shared__ __align__(16) u16t  s_se[16 * 72];
    __shared__ float s_b1w2[16][64];
    __shared__ float s_b2[16];
    __shared__ float s_q[128];
    __shared__ float s_h1wA[512], s_h1wB[384];
    __shared__ float s_h1bA[64], s_h1bB[64], s_bias3[64], s_hb2w[64];
    __shared__ float s_b1b[32], s_w2b[32], s_w1b[32];
    __shared__ float s_hb2bv;

    const int tid  = threadIdx.x;
    const int wave = tid >> 6;
    const int lane = tid & 63;
    const int lr = lane & 15, lg = lane >> 4;
    const int sbase = (blockIdx.x & 1023) * 16;
    const int o = wave * 16 + lr;

    // ---- B0 staging ----
    for (int i = tid; i < 16 * 28; i += 256) {
        int s = i / 28, c = i - s * 28;
        *(float4*)&s_x[s][c * 4] = *(const float4*)(states + (size_t)(sbase + s) * SDIM + c * 4);
    }
    if (tid < 224) {
        int s = tid / 14, j = tid - s * 14;
        const float* ap = states + (size_t)(sbase + s) * SDIM + 112 + j;
        float t = 0.f;
#pragma unroll
        for (int a = 0; a < 8; ++a) t += ap[a * 14];
        s_act[s][j] = t;
    }
    for (int i = tid; i < 512; i += 256) s_h1wA[i] = al_h1w[i];
    for (int i = tid; i < 384; i += 256) s_h1wB[i] = en_h1w[i];
    if (tid < 64) {
        s_h1bA[tid] = al_h1b[tid]; s_h1bB[tid] = en_h1b[tid];
        s_bias3[tid] = al_bias[tid] + en_bias[tid] + act_b[tid];
        s_hb2w[tid] = hb2_w[tid];
    }
    if (tid >= 64 && tid < 96)   s_b1b[tid - 64] = hb1_b[tid - 64];
    if (tid >= 96 && tid < 128)  s_w2b[tid - 96] = hw2_b[tid - 96];
    if (tid >= 128 && tid < 160) s_w1b[tid - 128] = hw1_b[tid - 128];
    if (tid == 160) s_hb2bv = hb2_b[0];
    if (tid >= 128) s_q[tid - 128] = qvals[(size_t)sbase * 8 + (tid - 128)];
    __syncthreads();                               // B0

    u16t* ps = (u16t*)s_un;

    // ---- P1: stage1 A + xsumA + zero pad ----
    if constexpr (PH >= 2) {
        stage1<8, KPA, 0>(s_x, ps, s_h1wA, s_h1bA[lane], wave, lane);
        if (tid < 128) {
            int s = tid >> 3, i = tid & 7;
            float t = 0.f;
#pragma unroll
            for (int a = 0; a < 8; ++a) t += s_x[s][a * 8 + i];
            ps[s * KPA + 512 + i] = bf1(t);
        } else {
            int idx = tid - 128;
            for (int u = idx; u < 192; u += 128) {
                int s = u / 12, r = u - s * 12;
                *(uint32_t*)&ps[s * KPA + 520 + r * 2] = 0u;
            }
        }
    }
    __syncthreads();                               // B1

    // ---- P2: GEMM A ----
    f32x4 accA = {0.f, 0.f, 0.f, 0.f};
    if constexpr (PH >= 3) {
        const u16t* arow = ps + lr * KPA + lg * 8;
        const bf16x8* wt8 = (const bf16x8*)wtA;
#pragma unroll 4
        for (int kk = 0; kk < 544; kk += 32) {
            bf16x8 av = *(const bf16x8*)(arow + kk);
            bf16x8 bv = wt8[((kk >> 3) + lg) * 64 + o];
            accA = __builtin_amdgcn_mfma_f32_16x16x32_bf16(av, bv, accA, 0, 0, 0);
        }
    }
    __syncthreads();                               // B2

    // ---- P3: hs issue + stage1 B + ext ----
    float4 hsr[8];
    if constexpr (PH >= 4) {
        const float4* hsv = (const float4*)(hs + (size_t)sbase * 512);
#pragma unroll
        for (int i = 0; i < 8; ++i) hsr[i] = hsv[i * 256 + tid];
        stage1<6, KPB, 64>(s_x, ps, s_h1wB, s_h1bB[lane], wave, lane);
        if (tid < 96) {
            int s = tid / 6, i = tid - (tid / 6) * 6;
            float t = 0.f;
#pragma unroll
            for (int a = 0; a < 8; ++a) t += s_x[s][64 + a * 6 + i];
            ps[s * KPB + 384 + i] = bf1(t);
        } else {
            int idx = tid - 96;
            for (int u = idx; u < 224; u += 160) {
                int s = u / 14, j = u - s * 14;
                ps[s * KPB + 390 + j] = bf1(s_act[s][j]);
            }
        }
        if (tid < 96) {
            int s = tid / 6, r = tid - (tid / 6) * 6;
            *(uint32_t*)&ps[s * KPB + 404 + r * 2] = 0u;
        }
    }
    __syncthreads();                               // B3

    // ---- P4: GEMM B + se ----
    if constexpr (PH >= 4) {
        f32x4 accB = {0.f, 0.f, 0.f, 0.f};
        const u16t* arow = ps + lr * KPB + lg * 8;
        const bf16x8* wt8 = (const bf16x8*)wtB;
#pragma unroll 4
        for (int kk = 0; kk < 416; kk += 32) {
            bf16x8 av = *(const bf16x8*)(arow + kk);
            bf16x8 bv = wt8[((kk >> 3) + lg) * 64 + o];
            accB = __builtin_amdgcn_mfma_f32_16x16x32_bf16(av, bv, accB, 0, 0, 0);
        }
#pragma unroll
        for (int j = 0; j < 4; ++j) {
            const int row = lg * 4 + j;
            float se = (accA[j] + accB[j]) * 0.125f + s_bias3[o];
            s_se[row * 72 + o] = bf1(fmaxf(se, 0.f));
        }
    }
    __syncthreads();                               // B4

    // ---- P5: hs->LDS | b1w2 | b2 ----
    u16t* s_hs = (u16t*)s_un;
    if constexpr (PH >= 5) {
#pragma unroll
        for (int i = 0; i < 8; ++i) {
            const int idx = i * 256 + tid;
            const int row = idx >> 4, c4 = idx & 15;
            uint2 p;
            p.x = pk2(hsr[i].x, hsr[i].y);
            p.y = pk2(hsr[i].z, hsr[i].w);
            *(uint2*)&s_hs[row * 72 + c4 * 4] = p;
        }
        {
            f32x4 acc = {0.f, 0.f, 0.f, 0.f};
            const u16t* serow = &s_se[lr * 72 + lg * 8];
            const bf16x8* wt8 = (const bf16x8*)wt2;
#pragma unroll
            for (int ks = 0; ks < 2; ++ks) {
                bf16x8 av = *(const bf16x8*)(serow + ks * 32);
                bf16x8 bv = wt8[(ks * 4 + lg) * 64 + o];
                acc = __builtin_amdgcn_mfma_f32_16x16x32_bf16(av, bv, acc, 0, 0, 0);
            }
#pragma unroll
            for (int j = 0; j < 4; ++j) {
                const int row = lg * 4 + j;
                float v = acc[j] + ((o < 32) ? s_b1b[o] : s_w2b[o - 32]);
                if (o >= 32) v = fabsf(v);
                s_b1w2[row][o] = v;
            }
        }
        {
            const int smp = wave * 4 + lg;
            float p = 0.f;
#pragma unroll
            for (int c = 0; c < 4; ++c) {
                const int oo = c * 16 + lr;
                p += lo16((uint32_t)s_se[smp * 72 + oo]) * s_hb2w[oo];
            }
            p += __shfl_xor(p, 1); p += __shfl_xor(p, 2);
            p += __shfl_xor(p, 4); p += __shfl_xor(p, 8);
            if (lr == 0) s_b2[smp] = p + s_hb2bv;
        }
    }
    __syncthreads();                               // B5

    // ---- P6: mix + out, or checksum ----
    if constexpr (PH >= 6) {
        bf16x8 bfr[2][2];
        {
            const bf16x8* wtm8 = (const bf16x8*)wtM;
#pragma unroll
            for (int n = 0; n < 2; ++n)
#pragma unroll
                for (int ks = 0; ks < 2; ++ks)
                    bfr[n][ks] = wtm8[(ks * 4 + lg) * 32 + n * 16 + lr];
        }
        const float zb0 = s_w1b[lr], zb1 = s_w1b[16 + lr];
        for (int t = wave * 2; t < wave * 2 + 2; ++t) {
            f32x4 d0 = {0.f,0.f,0.f,0.f}, d1 = {0.f,0.f,0.f,0.f};
#pragma unroll
            for (int ks = 0; ks < 2; ++ks) {
                bf16x8 av = *(const bf16x8*)&s_hs[(t * 16 + lr) * 72 + ks * 32 + lg * 8];
                d0 = __builtin_amdgcn_mfma_f32_16x16x32_bf16(av, bfr[0][ks], d0, 0, 0, 0);
                d1 = __builtin_amdgcn_mfma_f32_16x16x32_bf16(av, bfr[1][ks], d1, 0, 0, 0);
            }
            const int sloc = t * 2 + (lg >> 1);
            float z0[4], z1[4];
#pragma unroll
            for (int j = 0; j < 4; ++j) { z0[j] = d0[j] + zb0; z1[j] = d1[j] + zb1; }
            float m0 = fmaxf(fmaxf(z0[0], z0[1]), fmaxf(z0[2], z0[3]));
            float m1 = fmaxf(fmaxf(z1[0], z1[1]), fmaxf(z1[2], z1[3]));
            m0 = fmaxf(m0, __shfl_xor(m0, 16));
            m1 = fmaxf(m1, __shfl_xor(m1, 16));
            float qa[4];
            {
                float4 qv = *(const float4*)&s_q[sloc * 8 + (lg & 1) * 4];
                qa[0] = qv.x; qa[1] = qv.y; qa[2] = qv.z; qa[3] = qv.w;
            }
            float s0 = 0.f, s1 = 0.f, hp0 = 0.f, hp1 = 0.f;
#pragma unroll
            for (int j = 0; j < 4; ++j) {
                float e0 = __expf(z0[j] - m0), e1 = __expf(z1[j] - m1);
                s0 += e0; s1 += e1;
                hp0 += qa[j] * e0; hp1 += qa[j] * e1;
            }
            s0  += __shfl_xor(s0, 16);  s1  += __shfl_xor(s1, 16);
            hp0 += __shfl_xor(hp0, 16); hp1 += __shfl_xor(hp1, 16);
            const float b1_0 = s_b1w2[sloc][lr],      b1_1 = s_b1w2[sloc][16 + lr];
            const float w2_0 = s_b1w2[sloc][32 + lr], w2_1 = s_b1w2[sloc][48 + lr];
            float h0 = hp0 / s0 + b1_0; h0 = (h0 > 0.f) ? h0 : (__expf(h0) - 1.f);
            float h1 = hp1 / s1 + b1_1; h1 = (h1 > 0.f) ? h1 : (__expf(h1) - 1.f);
            float yp = h0 * w2_0 + h1 * w2_1;
            yp += __shfl_xor(yp, 1); yp += __shfl_xor(yp, 2);
            yp += __shfl_xor(yp, 4); yp += __shfl_xor(yp, 8);
            if (lr == 0 && (lg & 1) == 0) out[sbase + sloc] = yp + s_b2[sloc];
        }
    } else {
        // checksum keeps all executed phases live
        float chk = 0.f;
        if constexpr (PH == 1) {
            chk = s_x[lane & 15][tid % 112] + s_act[lane & 15][tid % 14]
                + s_h1wA[(tid * 2) & 511] + s_h1wB[tid % 384]
                + s_q[tid & 127] + s_bias3[lane] + s_b1b[lane & 31]
                + s_w2b[lane & 31] + s_w1b[lane & 31] + s_hb2w[lane] + s_hb2bv
                + s_h1bA[lane] + s_h1bB[lane];
        }
        if constexpr (PH == 2) {
            chk = lo16((uint32_t)ps[(tid & 15) * KPA + (tid * 7) % 544])
                + lo16((uint32_t)ps[lr * KPA + tid % 520])
                + lo16((uint32_t)ps[(tid & 15) * KPA + 512 + (tid & 7)]);
        }
        if constexpr (PH == 3) {
            chk = accA[0] + accA[1] + accA[2] + accA[3];
        }
        if constexpr (PH == 4) {
            chk = accA[0] + accA[1] + accA[2] + accA[3];
#pragma unroll
            for (int i = 0; i < 8; ++i) chk += hsr[i].x + hsr[i].y + hsr[i].z + hsr[i].w;
            chk += lo16((uint32_t)s_se[(tid & 15) * 72 + lane]);
        }
        if constexpr (PH == 5) {
            chk = s_b1w2[tid & 15][lane] + s_b2[tid & 15]
                + lo16((uint32_t)s_hs[(tid & 63) * 72 + lane]);
        }
        if (blockIdx.x < 1024)
            scratch[(size_t)(PH - 1) * 262144 + blockIdx.x * 256 + tid] = chk;
    }
}

extern "C" void kernel_launch(void* const* d_in, const int* in_sizes, int n_in,
                              void* d_out, int out_size, void* d_ws, size_t ws_size,
                              hipStream_t stream) {
    const float* qvals   = (const float*)d_in[0];
    const float* states  = (const float*)d_in[1];
    const float* hstates = (const float*)d_in[2];
    const float* hw1_w   = (const float*)d_in[3];
    const float* hw1_b   = (const float*)d_in[4];
    const float* en_h1w  = (const float*)d_in[5];
    const float* en_h1b  = (const float*)d_in[6];
    const float* en_h2w  = (const float*)d_in[7];
    const float* en_h2b  = (const float*)d_in[8];
    const float* en_bias = (const float*)d_in[9];
    const float* al_h1w  = (const float*)d_in[10];
    const float* al_h1b  = (const float*)d_in[11];
    const float* al_h2w  = (const float*)d_in[12];
    const float* al_h2b  = (const float*)d_in[13];
    const float* al_bias = (const float*)d_in[14];
    const float* act_w   = (const float*)d_in[15];
    const float* act_b   = (const float*)d_in[16];
    const float* hb1_w   = (const float*)d_in[17];
    const float* hb1_b   = (const float*)d_in[18];
    const float* hw2_w   = (const float*)d_in[19];
    const float* hw2_b   = (const float*)d_in[20];
    const float* hb2_w   = (const float*)d_in[21];
    const float* hb2_b   = (const float*)d_in[22];

    u16t* wtA = (u16t*)d_ws;
    u16t* wtB = wtA + 34816;
    u16t* wt2 = wtA + 61440;
    u16t* wtM = wtA + 65536;
    float* scratch = (float*)((char*)d_ws + (2u << 20));   // 2MB..7MB region

    prep_wt_kernel<<<64, 256, 0, stream>>>(al_h2w, en_h2w, al_h2b, en_h2b, act_w,
                                           hb1_w, hw2_w, hw1_w, wtA, wtB, wt2, wtM);

#define ARGS qvals, states, hstates, al_h1w, al_h1b, en_h1w, en_h1b, \
             al_bias, en_bias, act_b, hb1_b, hw2_b, hw1_b, hb2_w, hb2_b, \
             wtA, wtB, wt2, wtM, (float*)d_out, scratch
    fused_ab<1><<<32768, 256, 0, stream>>>(ARGS);   // staging only       x32
    fused_ab<2><<<12288, 256, 0, stream>>>(ARGS);   // +stage1A           x12
    fused_ab<3><<< 8192, 256, 0, stream>>>(ARGS);   // +GEMM A            x8
    fused_ab<4><<< 6144, 256, 0, stream>>>(ARGS);   // +stage1B+GEMMB+se  x6
    fused_ab<5><<< 5120, 256, 0, stream>>>(ARGS);   // +hsStore+b1w2+b2   x5
    fused_ab<6><<< 1024, 256, 0, stream>>>(ARGS);   // full, writes out   x1
#undef ARGS
}

// Round 16
// 38.766 us; speedup vs baseline: 9.9601x; 9.9601x over previous
//
#include <hip/hip_runtime.h>
#include <hip/hip_bf16.h>
#include <stdint.h>

typedef unsigned short u16t;
typedef float f32x4 __attribute__((ext_vector_type(4)));
typedef short bf16x8 __attribute__((ext_vector_type(8)));

#define SDIM 224

__device__ __forceinline__ float lo16(uint32_t w) { union { uint32_t u; float f; } v; v.u = w << 16; return v.f; }
__device__ __forceinline__ u16t bf1(float a) {
    union { __hip_bfloat16 h; u16t u; } c; c.h = __float2bfloat16(a); return c.u;
}
__device__ __forceinline__ uint32_t pk2(float a, float b) {
    union { __hip_bfloat162 h; uint32_t u; } c;
    c.h = __float22bfloat162_rn(make_float2(a, b));
    return c.u;
}

// ---------------------------------------------------------------------------
// Prep: pack GEMM B-operands, MFMA-frag order: buf[(kb*N+n)*8+j] = W[kb*8+j][n]
//  wtA: K=544: [0,512) h2wA (k=i*64+h), [512,520) h2bA rows, [520,544) zero
//  wtB: K=416: [0,384) h2wB, [384,390) h2bB, [390,404) act_w, [404,416) zero
//  wt2: K=64, N=64 (hb1_w | hw2_w);  wtM: K=64, N=32 (hw1_w)
// ---------------------------------------------------------------------------
__global__ void prep_wt_kernel(const float* __restrict__ h2wA, const float* __restrict__ h2wB,
                               const float* __restrict__ h2bA, const float* __restrict__ h2bB,
                               const float* __restrict__ actw,
                               const float* __restrict__ hb1w, const float* __restrict__ hw2w,
                               const float* __restrict__ hw1w,
                               u16t* __restrict__ wtA, u16t* __restrict__ wtB,
                               u16t* __restrict__ wt2, u16t* __restrict__ wtM)
{
    const int t0 = blockIdx.x * 256 + threadIdx.x, stride = gridDim.x * 256;
    for (int e = t0; e < 34816; e += stride) {
        int j = e & 7, n = (e >> 3) & 63, kb = e >> 9;
        int k = kb * 8 + j;
        float v = 0.f;
        if (k < 512)      { int h = k & 63, i = k >> 6; v = h2wA[h * 512 + i * 64 + n]; }
        else if (k < 520) v = h2bA[(k - 512) * 64 + n];
        wtA[e] = bf1(v);
    }
    for (int e = t0; e < 26624; e += stride) {
        int j = e & 7, n = (e >> 3) & 63, kb = e >> 9;
        int k = kb * 8 + j;
        float v = 0.f;
        if (k < 384)      { int h = k & 63, i = k >> 6; v = h2wB[h * 384 + i * 64 + n]; }
        else if (k < 390) v = h2bB[(k - 384) * 64 + n];
        else if (k < 404) v = actw[(k - 390) * 64 + n];
        wtB[e] = bf1(v);
    }
    for (int e = t0; e < 4096; e += stride) {
        int j = e & 7, n = (e >> 3) & 63, kb = e >> 9;
        int k = kb * 8 + j;
        float v = (n < 32) ? hb1w[k * 32 + n] : hw2w[k * 32 + (n - 32)];
        wt2[e] = bf1(v);
    }
    for (int e = t0; e < 2048; e += stride) {
        int j = e & 7, n = (e >> 3) & 31, kb = e >> 8;
        wtM[e] = bf1(hw1w[(kb * 8 + j) * 32 + n]);
    }
}

// ---------------------------------------------------------------------------
// stage1 from f32 x: psum[s][k=i*64+h] bf16, 4 samples/wave, lane = h.
// ---------------------------------------------------------------------------
template<int DIN, int KP, int FOFF>
__device__ __forceinline__ void stage1(const float (*sx)[112], u16t* __restrict__ ps,
                                       const float* __restrict__ s_h1w, float b1r,
                                       int wave, int lane)
{
    float w1r[DIN];
#pragma unroll
    for (int i = 0; i < DIN; ++i) w1r[i] = s_h1w[i * 64 + lane];
#pragma unroll 1
    for (int ss = 0; ss < 4; ++ss) {
        const int s = wave * 4 + ss;
        const float* xr = &sx[s][FOFF];
        float psv[DIN];
#pragma unroll
        for (int i = 0; i < DIN; ++i) psv[i] = 0.f;
#pragma unroll
        for (int a = 0; a < 8; ++a) {
            float x[DIN];
            if constexpr (DIN == 8) {
                float4 v0 = *(const float4*)(xr + a * 8);
                float4 v1 = *(const float4*)(xr + a * 8 + 4);
                x[0] = v0.x; x[1] = v0.y; x[2] = v0.z; x[3] = v0.w;
                x[4] = v1.x; x[5] = v1.y; x[6] = v1.z; x[7] = v1.w;
            } else {
                float2 v0 = *(const float2*)(xr + a * 6);
                float2 v1 = *(const float2*)(xr + a * 6 + 2);
                float2 v2 = *(const float2*)(xr + a * 6 + 4);
                x[0] = v0.x; x[1] = v0.y; x[2] = v1.x; x[3] = v1.y; x[4] = v2.x; x[5] = v2.y;
            }
            float hacc = b1r;
#pragma unroll
            for (int i = 0; i < DIN; ++i) hacc += x[i] * w1r[i];
            hacc = fmaxf(hacc, 0.f);
#pragma unroll
            for (int i = 0; i < DIN; ++i) psv[i] += hacc * x[i];
        }
#pragma unroll
        for (int i = 0; i < DIN; i += 2) {
            union { __hip_bfloat162 h; struct { u16t lo, hi; } w; } c;
            c.h = __float22bfloat162_rn(make_float2(psv[i], psv[i + 1]));
            ps[s * KP + i * 64 + lane]       = c.w.lo;
            ps[s * KP + (i + 1) * 64 + lane] = c.w.hi;
        }
    }
}

// ---------------------------------------------------------------------------
// Fused mixer: R14 structure + B-fragment REGISTER PREFETCH.
// Every GEMM's B-operands are loaded into VGPRs one phase ahead (L2 latency
// hidden under the preceding VALU phase); MFMA loops run from registers+LDS.
// ---------------------------------------------------------------------------
__global__ __launch_bounds__(256, 4)
void fused_mixer(const float* __restrict__ qvals, const float* __restrict__ states,
                 const float* __restrict__ hs,
                 const float* __restrict__ al_h1w, const float* __restrict__ al_h1b,
                 const float* __restrict__ en_h1w, const float* __restrict__ en_h1b,
                 const float* __restrict__ al_bias, const float* __restrict__ en_bias,
                 const float* __restrict__ act_b,
                 const float* __restrict__ hb1_b, const float* __restrict__ hw2_b,
                 const float* __restrict__ hw1_b, const float* __restrict__ hb2_w,
                 const float* __restrict__ hb2_b,
                 const u16t* __restrict__ wtA, const u16t* __restrict__ wtB,
                 const u16t* __restrict__ wt2, const u16t* __restrict__ wtM,
                 float* __restrict__ out)
{
    constexpr int KPA = 552, KPB = 424;
    __shared__ __align__(16) char  s_un[18432];    // psumA(17664)/psumB(13568)/hs(18432)
    __shared__ __align__(16) float s_x[16][112];
    __shared__ float s_act[16][14];
    __shared__ __align__(16) u16t  s_se[16 * 72];
    __shared__ float s_b1w2[16][64];
    __shared__ float s_b2[16];
    __shared__ float s_q[128];
    __shared__ float s_h1wA[512], s_h1wB[384];
    __shared__ float s_h1bA[64], s_h1bB[64], s_bias3[64], s_hb2w[64];
    __shared__ float s_b1b[32], s_w2b[32], s_w1b[32];
    __shared__ float s_hb2bv;

    const int tid  = threadIdx.x;
    const int wave = tid >> 6;
    const int lane = tid & 63;
    const int lr = lane & 15, lg = lane >> 4;
    const int sbase = blockIdx.x * 16;
    const int o = wave * 16 + lr;                  // this thread's output column

    // ---- B0 staging ----
    for (int i = tid; i < 16 * 28; i += 256) {
        int s = i / 28, c = i - s * 28;
        *(float4*)&s_x[s][c * 4] = *(const float4*)(states + (size_t)(sbase + s) * SDIM + c * 4);
    }
    if (tid < 224) {
        int s = tid / 14, j = tid - (tid / 14) * 14;
        const float* ap = states + (size_t)(sbase + s) * SDIM + 112 + j;
        float t = 0.f;
#pragma unroll
        for (int a = 0; a < 8; ++a) t += ap[a * 14];
        s_act[s][j] = t;
    }
    for (int i = tid; i < 512; i += 256) s_h1wA[i] = al_h1w[i];
    for (int i = tid; i < 384; i += 256) s_h1wB[i] = en_h1w[i];
    if (tid < 64) {
        s_h1bA[tid] = al_h1b[tid]; s_h1bB[tid] = en_h1b[tid];
        s_bias3[tid] = al_bias[tid] + en_bias[tid] + act_b[tid];
        s_hb2w[tid] = hb2_w[tid];
    }
    if (tid >= 64 && tid < 96)   s_b1b[tid - 64] = hb1_b[tid - 64];
    if (tid >= 96 && tid < 128)  s_w2b[tid - 96] = hw2_b[tid - 96];
    if (tid >= 128 && tid < 160) s_w1b[tid - 128] = hw1_b[tid - 128];
    if (tid == 160) s_hb2bv = hb2_b[0];
    if (tid >= 128) s_q[tid - 128] = qvals[(size_t)sbase * 8 + (tid - 128)];
    __syncthreads();                               // B0

    u16t* ps = (u16t*)s_un;

    // ---- prefetch GEMM-A B-fragments (L2 latency hides under stage1A) ----
    bf16x8 bvA[17];
    {
        const bf16x8* wt8 = (const bf16x8*)wtA;
#pragma unroll
        for (int t = 0; t < 17; ++t) bvA[t] = wt8[(t * 4 + lg) * 64 + o];
    }

    // ---- P1: stage1 A + xsumA rows + zero pad ----
    stage1<8, KPA, 0>(s_x, ps, s_h1wA, s_h1bA[lane], wave, lane);
    if (tid < 128) {
        int s = tid >> 3, i = tid & 7;
        float t = 0.f;
#pragma unroll
        for (int a = 0; a < 8; ++a) t += s_x[s][a * 8 + i];
        ps[s * KPA + 512 + i] = bf1(t);
    } else {
        int idx = tid - 128;
        for (int u = idx; u < 192; u += 128) {
            int s = u / 12, r = u - (u / 12) * 12;
            *(uint32_t*)&ps[s * KPA + 520 + r * 2] = 0u;
        }
    }
    __syncthreads();                               // B1

    // ---- P2: GEMM A from registers, M=16, N=16/wave, K=544 ----
    f32x4 accA = {0.f, 0.f, 0.f, 0.f};
    {
        const u16t* arow = ps + lr * KPA + lg * 8;
#pragma unroll
        for (int t = 0; t < 17; ++t) {
            bf16x8 av = *(const bf16x8*)(arow + t * 32);
            accA = __builtin_amdgcn_mfma_f32_16x16x32_bf16(av, bvA[t], accA, 0, 0, 0);
        }
    }
    __syncthreads();                               // B2 (psumA free)

    // ---- P3: prefetch GEMM-B fragments; stage1 B + ext rows; issue hs ----
    bf16x8 bvB[13];
    {
        const bf16x8* wt8 = (const bf16x8*)wtB;
#pragma unroll
        for (int t = 0; t < 13; ++t) bvB[t] = wt8[(t * 4 + lg) * 64 + o];
    }
    stage1<6, KPB, 64>(s_x, ps, s_h1wB, s_h1bB[lane], wave, lane);
    if (tid < 96) {
        int s = tid / 6, i = tid - (tid / 6) * 6;
        float t = 0.f;
#pragma unroll
        for (int a = 0; a < 8; ++a) t += s_x[s][64 + a * 6 + i];
        ps[s * KPB + 384 + i] = bf1(t);
    } else {
        int idx = tid - 96;
        for (int u = idx; u < 224; u += 160) {
            int s = u / 14, j = u - (u / 14) * 14;
            ps[s * KPB + 390 + j] = bf1(s_act[s][j]);
        }
    }
    if (tid < 96) {
        int s = tid / 6, r = tid - (tid / 6) * 6;
        *(uint32_t*)&ps[s * KPB + 404 + r * 2] = 0u;
    }
    float4 hsr[8];                                 // issued after stage1B (reg pressure)
    {
        const float4* hsv = (const float4*)(hs + (size_t)sbase * 512);
#pragma unroll
        for (int i = 0; i < 8; ++i) hsr[i] = hsv[i * 256 + tid];
    }
    __syncthreads();                               // B3

    // ---- P4: prefetch wt2 fragments; GEMM B from regs; se epilogue ----
    bf16x8 bvW[2];
    {
        const bf16x8* wt8 = (const bf16x8*)wt2;
#pragma unroll
        for (int ks = 0; ks < 2; ++ks) bvW[ks] = wt8[(ks * 4 + lg) * 64 + o];
    }
    {
        f32x4 accB = {0.f, 0.f, 0.f, 0.f};
        const u16t* arow = ps + lr * KPB + lg * 8;
#pragma unroll
        for (int t = 0; t < 13; ++t) {
            bf16x8 av = *(const bf16x8*)(arow + t * 32);
            accB = __builtin_amdgcn_mfma_f32_16x16x32_bf16(av, bvB[t], accB, 0, 0, 0);
        }
#pragma unroll
        for (int j = 0; j < 4; ++j) {
            const int row = lg * 4 + j;
            float se = (accA[j] + accB[j]) * 0.125f + s_bias3[o];
            s_se[row * 72 + o] = bf1(fmaxf(se, 0.f));
        }
    }
    __syncthreads();                               // B4 (se ready, psumB dead)

    // ---- P5: prefetch wtM fragments; hs->LDS; b1w2 MFMA; b2 reduce ----
    bf16x8 bfr[2][2];
    {
        const bf16x8* wtm8 = (const bf16x8*)wtM;
#pragma unroll
        for (int n = 0; n < 2; ++n)
#pragma unroll
            for (int ks = 0; ks < 2; ++ks)
                bfr[n][ks] = wtm8[(ks * 4 + lg) * 32 + n * 16 + lr];
    }
    u16t* s_hs = (u16t*)s_un;
    {
#pragma unroll
        for (int i = 0; i < 8; ++i) {
            const int idx = i * 256 + tid;
            const int row = idx >> 4, c4 = idx & 15;
            uint2 p;
            p.x = pk2(hsr[i].x, hsr[i].y);
            p.y = pk2(hsr[i].z, hsr[i].w);
            *(uint2*)&s_hs[row * 72 + c4 * 4] = p;
        }
    }
    {   // b1w2: M=16, K=64, N=16/wave (B from regs)
        f32x4 acc = {0.f, 0.f, 0.f, 0.f};
        const u16t* serow = &s_se[lr * 72 + lg * 8];
#pragma unroll
        for (int ks = 0; ks < 2; ++ks) {
            bf16x8 av = *(const bf16x8*)(serow + ks * 32);
            acc = __builtin_amdgcn_mfma_f32_16x16x32_bf16(av, bvW[ks], acc, 0, 0, 0);
        }
#pragma unroll
        for (int j = 0; j < 4; ++j) {
            const int row = lg * 4 + j;
            float v = acc[j] + ((o < 32) ? s_b1b[o] : s_w2b[o - 32]);
            if (o >= 32) v = fabsf(v);
            s_b1w2[row][o] = v;
        }
    }
    {   // b2: group (wave,lg) reduces sample smp over 64 cols
        const int smp = wave * 4 + lg;
        float p = 0.f;
#pragma unroll
        for (int c = 0; c < 4; ++c) {
            const int oo = c * 16 + lr;
            p += lo16((uint32_t)s_se[smp * 72 + oo]) * s_hb2w[oo];
        }
        p += __shfl_xor(p, 1); p += __shfl_xor(p, 2);
        p += __shfl_xor(p, 4); p += __shfl_xor(p, 8);
        if (lr == 0) s_b2[smp] = p + s_hb2bv;
    }
    __syncthreads();                               // B5

    // ---- P6: mix (z MFMA from prefetched bfr, softmax, q-mix, ELU, dot) ----
    const float zb0 = s_w1b[lr], zb1 = s_w1b[16 + lr];

    for (int t = wave * 2; t < wave * 2 + 2; ++t) {
        f32x4 d0 = {0.f,0.f,0.f,0.f}, d1 = {0.f,0.f,0.f,0.f};
#pragma unroll
        for (int ks = 0; ks < 2; ++ks) {
            bf16x8 av = *(const bf16x8*)&s_hs[(t * 16 + lr) * 72 + ks * 32 + lg * 8];
            d0 = __builtin_amdgcn_mfma_f32_16x16x32_bf16(av, bfr[0][ks], d0, 0, 0, 0);
            d1 = __builtin_amdgcn_mfma_f32_16x16x32_bf16(av, bfr[1][ks], d1, 0, 0, 0);
        }
        const int sloc = t * 2 + (lg >> 1);
        float z0[4], z1[4];
#pragma unroll
        for (int j = 0; j < 4; ++j) { z0[j] = d0[j] + zb0; z1[j] = d1[j] + zb1; }
        float m0 = fmaxf(fmaxf(z0[0], z0[1]), fmaxf(z0[2], z0[3]));
        float m1 = fmaxf(fmaxf(z1[0], z1[1]), fmaxf(z1[2], z1[3]));
        m0 = fmaxf(m0, __shfl_xor(m0, 16));
        m1 = fmaxf(m1, __shfl_xor(m1, 16));
        float qa[4];
        {
            float4 qv = *(const float4*)&s_q[sloc * 8 + (lg & 1) * 4];
            qa[0] = qv.x; qa[1] = qv.y; qa[2] = qv.z; qa[3] = qv.w;
        }
        float s0 = 0.f, s1 = 0.f, hp0 = 0.f, hp1 = 0.f;
#pragma unroll
        for (int j = 0; j < 4; ++j) {
            float e0 = __expf(z0[j] - m0), e1 = __expf(z1[j] - m1);
            s0 += e0; s1 += e1;
            hp0 += qa[j] * e0; hp1 += qa[j] * e1;
        }
        s0  += __shfl_xor(s0, 16);  s1  += __shfl_xor(s1, 16);
        hp0 += __shfl_xor(hp0, 16); hp1 += __shfl_xor(hp1, 16);

        const float b1_0 = s_b1w2[sloc][lr],      b1_1 = s_b1w2[sloc][16 + lr];
        const float w2_0 = s_b1w2[sloc][32 + lr], w2_1 = s_b1w2[sloc][48 + lr];
        float h0 = hp0 / s0 + b1_0; h0 = (h0 > 0.f) ? h0 : (__expf(h0) - 1.f);
        float h1 = hp1 / s1 + b1_1; h1 = (h1 > 0.f) ? h1 : (__expf(h1) - 1.f);
        float yp = h0 * w2_0 + h1 * w2_1;
        yp += __shfl_xor(yp, 1); yp += __shfl_xor(yp, 2);
        yp += __shfl_xor(yp, 4); yp += __shfl_xor(yp, 8);
        if (lr == 0 && (lg & 1) == 0) out[sbase + sloc] = yp + s_b2[sloc];
    }
}

extern "C" void kernel_launch(void* const* d_in, const int* in_sizes, int n_in,
                              void* d_out, int out_size, void* d_ws, size_t ws_size,
                              hipStream_t stream) {
    const float* qvals   = (const float*)d_in[0];
    const float* states  = (const float*)d_in[1];
    const float* hstates = (const float*)d_in[2];
    const float* hw1_w   = (const float*)d_in[3];
    const float* hw1_b   = (const float*)d_in[4];
    const float* en_h1w  = (const float*)d_in[5];
    const float* en_h1b  = (const float*)d_in[6];
    const float* en_h2w  = (const float*)d_in[7];
    const float* en_h2b  = (const float*)d_in[8];
    const float* en_bias = (const float*)d_in[9];
    const float* al_h1w  = (const float*)d_in[10];
    const float* al_h1b  = (const float*)d_in[11];
    const float* al_h2w  = (const float*)d_in[12];
    const float* al_h2b  = (const float*)d_in[13];
    const float* al_bias = (const float*)d_in[14];
    const float* act_w   = (const float*)d_in[15];
    const float* act_b   = (const float*)d_in[16];
    const float* hb1_w   = (const float*)d_in[17];
    const float* hb1_b   = (const float*)d_in[18];
    const float* hw2_w   = (const float*)d_in[19];
    const float* hw2_b   = (const float*)d_in[20];
    const float* hb2_w   = (const float*)d_in[21];
    const float* hb2_b   = (const float*)d_in[22];

    // ws (u16): wtA@0 (34816) | wtB@34816 (26624) | wt2@61440 (4096) | wtM@65536 (2048)
    u16t* wtA = (u16t*)d_ws;
    u16t* wtB = wtA + 34816;
    u16t* wt2 = wtA + 61440;
    u16t* wtM = wtA + 65536;

    prep_wt_kernel<<<64, 256, 0, stream>>>(al_h2w, en_h2w, al_h2b, en_h2b, act_w,
                                           hb1_w, hw2_w, hw1_w, wtA, wtB, wt2, wtM);
    fused_mixer<<<1024, 256, 0, stream>>>(qvals, states, hstates,
                                          al_h1w, al_h1b, en_h1w, en_h1b,
                                          al_bias, en_bias, act_b,
                                          hb1_b, hw2_b, hw1_b, hb2_w, hb2_b,
                                          wtA, wtB, wt2, wtM, (float*)d_out);
}